// Round 6
// baseline (126.317 us; speedup 1.0000x reference)
//
#include <hip/hip_runtime.h>
#include <hip/hip_bf16.h>
#include <math.h>

#define N_NODES 10000
#define KNBR    16
#define EDGEF   32
#define HID     64
#define MULT    8
#define NL      2
#define DIM     4
#define OUT_MULT 24
#define NHEADS  4
#define HEAD_DIM 8
#define E_TOT   (N_NODES*KNBR)

#define EPB 128
#define TPB 256
#define NSLICE 33            // K' = 1056 = 33 slices of 32 (last slice carries b2, zero-padded)

typedef float    f32x4 __attribute__((ext_vector_type(4)));
typedef _Float16 f16x8 __attribute__((ext_vector_type(8)));

// ws layout: wsh (fp16 weight frags) @0 ; t2g (f32, E x 48) @ T2_OFF bytes
#define BF1_HALVES (4*64*8)
#define BF2_HALVES (3*NSLICE*64*8)
#define WS_HALVES  (BF1_HALVES + BF2_HALVES)
#define T2_OFF     131072     // bytes; > WS_HALVES*2 = 105472, aligned

// ---------------- prep: fragment-ready fp16 weights into d_ws ----------------
__global__ __launch_bounds__(256)
void esa_prep(const float* __restrict__ W1, const float* __restrict__ W2,
              const float* __restrict__ b2, _Float16* __restrict__ wsh)
{
    int i = blockIdx.x * 256 + threadIdx.x;
    if (i >= WS_HALVES) return;
    float v;
    if (i < BF1_HALVES) {
        int j = i & 7, lane = (i >> 3) & 63, t = i >> 9;
        int k = ((lane >> 4) << 3) + j;          // 0..31
        int n = (t << 4) + (lane & 15);          // 0..63
        v = W1[n * EDGEF + k];
    } else {
        int i2 = i - BF1_HALVES;
        int j = i2 & 7, lane = (i2 >> 3) & 63;
        int st = i2 >> 9;                        // t*33 + s
        int s = st % NSLICE, t = st / NSLICE;
        int k = (s << 5) + ((lane >> 4) << 3) + j;   // 0..1055
        int n = (t << 4) + (lane & 15);              // oml 0..47
        if (k < 1024)      v = W2[(n * 16 + (k >> 6)) * HID + (k & 63)];
        else if (k < 1040) v = b2[n * 16 + (k - 1024)];
        else               v = 0.f;
    }
    wsh[i] = (_Float16)v;
}

// ---------------- kernel A: edge GEMM -> t2g (f32) ----------------
// LDS: h [128][72] f16 @0 (18432) | tp [128][16] f16 @18432 (4096) = 22528 B
__global__ __launch_bounds__(TPB, 4)
void esa_gemm(const float* __restrict__ basis1, const float* __restrict__ edge_feats,
              const float* __restrict__ f, const float* __restrict__ b1,
              const int* __restrict__ nbr, const _Float16* __restrict__ wsh,
              float* __restrict__ t2g)
{
    __shared__ __align__(16) unsigned char smem[22528];
    _Float16* hls = (_Float16*)smem;                    // stride 72 f16
    _Float16* tpl = (_Float16*)(smem + 18432);          // stride 16 f16

    const int tid  = threadIdx.x;
    const int eb   = blockIdx.x * EPB;
    const int lane = tid & 63;
    const int w    = tid >> 6;
    const int lo   = lane & 15, hi = lane >> 4;

    // ===== phase 0: tp (tensor-product coeffs) =====
    {
        int el = tid >> 1, hf = tid & 1;
        int e  = eb + el;
        int src = nbr[e];
        const float4* b1p = (const float4*)(basis1 + (size_t)e * 8);
        float4 u0 = b1p[0], u1 = b1p[1];                 // [d][l] layout
        float bl0[4] = {u0.x, u0.z, u1.x, u1.z};         // l=0, d=0..3
        float bl1[4] = {u0.y, u0.w, u1.y, u1.w};         // l=1
        const float4* fp = (const float4*)(f + (size_t)src * 32 + hf * 16);
        _Float16 tpv[8];
        #pragma unroll
        for (int mm = 0; mm < 4; ++mm) {
            float4 fv = fp[mm];
            float a0 = fv.x*bl0[0] + fv.y*bl0[1] + fv.z*bl0[2] + fv.w*bl0[3];
            float a1 = fv.x*bl1[0] + fv.y*bl1[1] + fv.z*bl1[2] + fv.w*bl1[3];
            tpv[mm*2+0] = (_Float16)a0;
            tpv[mm*2+1] = (_Float16)a1;
        }
        *(f16x8*)(tpl + el*16 + hf*8) = *(f16x8*)tpv;
    }

    // ===== phase 0b: MLP1 via MFMA  h = relu(ef @ W1^T + b1) =====
    {
        float b1v[4];
        #pragma unroll
        for (int t = 0; t < 4; ++t) b1v[t] = b1[t*16 + lo];
        f16x8 afr[2];
        #pragma unroll
        for (int mt = 0; mt < 2; ++mt) {
            size_t eg = (size_t)(eb + w*32 + mt*16 + lo);
            const float4* p = (const float4*)(edge_feats + eg*32 + hi*8);
            float4 x0 = p[0], x1 = p[1];
            f16x8 a;
            a[0]=(_Float16)x0.x; a[1]=(_Float16)x0.y; a[2]=(_Float16)x0.z; a[3]=(_Float16)x0.w;
            a[4]=(_Float16)x1.x; a[5]=(_Float16)x1.y; a[6]=(_Float16)x1.z; a[7]=(_Float16)x1.w;
            afr[mt] = a;
        }
        #pragma unroll
        for (int t = 0; t < 4; ++t) {
            f16x8 bfr = *(const f16x8*)(wsh + ((size_t)(t*64 + lane)) * 8);
            #pragma unroll
            for (int mt = 0; mt < 2; ++mt) {
                f32x4 acc = {0.f, 0.f, 0.f, 0.f};
                acc = __builtin_amdgcn_mfma_f32_16x16x32_f16(afr[mt], bfr, acc, 0, 0, 0);
                #pragma unroll
                for (int r = 0; r < 4; ++r) {
                    float hv = acc[r] + b1v[t];
                    hv = hv > 0.f ? hv : 0.f;
                    int el = w*32 + mt*16 + hi*4 + r;
                    hls[el*72 + t*16 + lo] = (_Float16)hv;
                }
            }
        }
    }
    __syncthreads();

    // ===== phase 1: main GEMM  t2[e,oml] = sum_k' A'[e,k'] B'[k',oml] =====
    {
        f32x4 acc[2][3];
        #pragma unroll
        for (int mt = 0; mt < 2; ++mt)
            #pragma unroll
            for (int t = 0; t < 3; ++t)
                acc[mt][t] = (f32x4){0.f, 0.f, 0.f, 0.f};

        const _Float16* Bf2 = wsh + BF1_HALVES;
        const int e0 = w*32 + lo;
        const int e1 = e0 + 16;
        const _Float16* hp0 = hls + e0*72 + hi*8;
        const _Float16* hp1 = hls + e1*72 + hi*8;
        f16x8 tp0a = *(const f16x8*)(tpl + e0*16);
        f16x8 tp0b = *(const f16x8*)(tpl + e0*16 + 8);
        f16x8 tp1a = *(const f16x8*)(tpl + e1*16);
        f16x8 tp1b = *(const f16x8*)(tpl + e1*16 + 8);

        #pragma unroll
        for (int sp = 0; sp < 16; ++sp) {
            _Float16 t0 = (sp < 8) ? tp0a[sp & 7] : tp0b[sp & 7];
            _Float16 t1 = (sp < 8) ? tp1a[sp & 7] : tp1b[sp & 7];
            f16x8 ts0 = {t0,t0,t0,t0,t0,t0,t0,t0};
            f16x8 ts1 = {t1,t1,t1,t1,t1,t1,t1,t1};
            #pragma unroll
            for (int sh = 0; sh < 2; ++sh) {
                const int s = sp*2 + sh;
                f16x8 bfr[3];
                #pragma unroll
                for (int t = 0; t < 3; ++t)
                    bfr[t] = *(const f16x8*)(Bf2 + ((size_t)((t*NSLICE + s)*64 + lane)) * 8);
                f16x8 h0 = *(const f16x8*)(hp0 + sh*32);
                f16x8 h1 = *(const f16x8*)(hp1 + sh*32);
                f16x8 a0 = h0 * ts0;
                f16x8 a1 = h1 * ts1;
                #pragma unroll
                for (int t = 0; t < 3; ++t) {
                    acc[0][t] = __builtin_amdgcn_mfma_f32_16x16x32_f16(a0, bfr[t], acc[0][t], 0, 0, 0);
                    acc[1][t] = __builtin_amdgcn_mfma_f32_16x16x32_f16(a1, bfr[t], acc[1][t], 0, 0, 0);
                }
            }
        }
        // bias slice s=32: A' = tp (hi<2), B' = b2 frags
        {
            f16x8 z = {(_Float16)0,(_Float16)0,(_Float16)0,(_Float16)0,
                       (_Float16)0,(_Float16)0,(_Float16)0,(_Float16)0};
            f16x8 a0 = (hi == 0) ? tp0a : (hi == 1) ? tp0b : z;
            f16x8 a1 = (hi == 0) ? tp1a : (hi == 1) ? tp1b : z;
            #pragma unroll
            for (int t = 0; t < 3; ++t) {
                f16x8 bfr = *(const f16x8*)(Bf2 + ((size_t)((t*NSLICE + 32)*64 + lane)) * 8);
                acc[0][t] = __builtin_amdgcn_mfma_f32_16x16x32_f16(a0, bfr, acc[0][t], 0, 0, 0);
                acc[1][t] = __builtin_amdgcn_mfma_f32_16x16x32_f16(a1, bfr, acc[1][t], 0, 0, 0);
            }
        }
        // write t2 rows to global (f32, row-major [E][48]); lanes lo cover 64B segments
        #pragma unroll
        for (int mt = 0; mt < 2; ++mt)
            #pragma unroll
            for (int t = 0; t < 3; ++t)
                #pragma unroll
                for (int r = 0; r < 4; ++r)
                    t2g[(size_t)(eb + w*32 + mt*16 + hi*4 + r)*48 + t*16 + lo] = acc[mt][t][r];
    }
}

// ---------------- kernel B: per-node attention ----------------
// t2 columns are oml = om*2+l: k_ -> oml [0,16), q_ -> [16,32), v_ -> [32,48)
__global__ __launch_bounds__(256)
void esa_attn(const float* __restrict__ t2g, const float* __restrict__ basis2,
              float* __restrict__ out)
{
    const int tid  = threadIdx.x;
    const int w    = tid >> 6;
    const int lane = tid & 63;
    const int node = blockIdx.x * 4 + w;
    const int kk   = lane >> 2, hh = lane & 3;
    const int e    = node * KNBR + kk;

    const float* trow = t2g + (size_t)e * 48;
    float4 tk = *(const float4*)(trow + hh*4);
    float4 tq = *(const float4*)(trow + 16 + hh*4);
    float4 tv = *(const float4*)(trow + 32 + hh*4);
    float4 bl0 = *(const float4*)(basis2 + (size_t)e * 8);
    float4 bl1 = *(const float4*)(basis2 + (size_t)e * 8 + 4);

    float k8[8], q8[8], v8[8];
    const float* B0 = (const float*)&bl0;
    const float* B1 = (const float*)&bl1;
    #pragma unroll
    for (int d = 0; d < 4; ++d) {
        k8[d]   = tk.x*B0[d] + tk.y*B1[d];
        k8[4+d] = tk.z*B0[d] + tk.w*B1[d];
        q8[d]   = tq.x*B0[d] + tq.y*B1[d];
        q8[4+d] = tq.z*B0[d] + tq.w*B1[d];
        v8[d]   = tv.x*B0[d] + tv.y*B1[d];
        v8[4+d] = tv.z*B0[d] + tv.w*B1[d];
    }
    float qn[8];
    #pragma unroll
    for (int i = 0; i < 8; ++i) qn[i] = q8[i];
    #pragma unroll
    for (int m = 4; m <= 32; m <<= 1)
        #pragma unroll
        for (int i = 0; i < 8; ++i) qn[i] += __shfl_xor(qn[i], m);
    float s = 0.f;
    #pragma unroll
    for (int i = 0; i < 8; ++i) s += qn[i]*k8[i];
    s *= 0.0220970869120796f;   // (1/16) * 8^-0.5

    float mx = s;
    #pragma unroll
    for (int m = 4; m <= 32; m <<= 1) mx = fmaxf(mx, __shfl_xor(mx, m));
    float ex = __expf(s - mx);
    float den = ex;
    #pragma unroll
    for (int m = 4; m <= 32; m <<= 1) den += __shfl_xor(den, m);
    float wgt = ex / den;

    float o[8];
    #pragma unroll
    for (int i = 0; i < 8; ++i) o[i] = wgt * v8[i];
    #pragma unroll
    for (int m = 4; m <= 32; m <<= 1)
        #pragma unroll
        for (int i = 0; i < 8; ++i) o[i] += __shfl_xor(o[i], m);
    if (kk == 0) {
        float4* dst = (float4*)(out + (size_t)node*32 + hh*8);
        dst[0] = make_float4(o[0], o[1], o[2], o[3]);
        dst[1] = make_float4(o[4], o[5], o[6], o[7]);
    }
}

extern "C" void kernel_launch(void* const* d_in, const int* in_sizes, int n_in,
                              void* d_out, int out_size, void* d_ws, size_t ws_size,
                              hipStream_t stream) {
    const float* basis1     = (const float*)d_in[0];
    const float* basis2     = (const float*)d_in[1];
    const float* edge_feats = (const float*)d_in[2];
    const float* f          = (const float*)d_in[3];
    const float* W1         = (const float*)d_in[4];
    const float* b1         = (const float*)d_in[5];
    const float* W2         = (const float*)d_in[6];
    const float* b2         = (const float*)d_in[7];
    const int*   nbr        = (const int*)d_in[8];
    float* out = (float*)d_out;
    _Float16* wsh = (_Float16*)d_ws;
    float* t2g = (float*)((char*)d_ws + T2_OFF);

    esa_prep<<<(WS_HALVES + 255)/256, 256, 0, stream>>>(W1, W2, b2, wsh);
    esa_gemm<<<E_TOT/EPB, TPB, 0, stream>>>(basis1, edge_feats, f, b1, nbr, wsh, t2g);
    esa_attn<<<N_NODES/4, 256, 0, stream>>>(t2g, basis2, out);
}